// Round 1
// baseline (119.596 us; speedup 1.0000x reference)
//
#include <hip/hip_runtime.h>

#define L 65
#define BINS (L * L)

// ---------------- Kernel 1: per-block LDS histogram ----------------
__global__ void hist_kernel(const int* __restrict__ pred,
                            const int* __restrict__ truem,
                            unsigned int* __restrict__ block_hist,
                            int n, int n4) {
    __shared__ unsigned int sh[BINS];
    for (int i = threadIdx.x; i < BINS; i += blockDim.x) sh[i] = 0u;
    __syncthreads();

    const int4* p4 = (const int4*)pred;
    const int4* t4 = (const int4*)truem;
    int stride = gridDim.x * blockDim.x;
    int gtid = blockIdx.x * blockDim.x + threadIdx.x;

    for (int i = gtid; i < n4; i += stride) {
        int4 p = p4[i];
        int4 t = t4[i];
        atomicAdd(&sh[p.x * L + t.x], 1u);
        atomicAdd(&sh[p.y * L + t.y], 1u);
        atomicAdd(&sh[p.z * L + t.z], 1u);
        atomicAdd(&sh[p.w * L + t.w], 1u);
    }
    // scalar tail (n not divisible by 4)
    for (int i = n4 * 4 + gtid; i < n; i += stride) {
        atomicAdd(&sh[pred[i] * L + truem[i]], 1u);
    }
    __syncthreads();

    unsigned int* dst = block_hist + (size_t)blockIdx.x * BINS;
    for (int i = threadIdx.x; i < BINS; i += blockDim.x) dst[i] = sh[i];
}

// ---------------- Kernel 2: reduce per-block hists -> float conf ----------------
__global__ void reduce_kernel(const unsigned int* __restrict__ block_hist,
                              float* __restrict__ conf, int nb) {
    int bin = blockIdx.x * blockDim.x + threadIdx.x;
    if (bin >= BINS) return;
    unsigned int s = 0u;
    for (int b = 0; b < nb; ++b) s += block_hist[(size_t)b * BINS + bin];
    conf[bin] = (float)s;
}

// ---------------- Kernel 3: tiny IoU epilogue ----------------
__global__ void finalize_kernel(const float* __restrict__ confg,
                                float* __restrict__ out) {
    __shared__ float conf[BINS];
    __shared__ float area_p[L];
    __shared__ float area_t[L];
    __shared__ float contrib[256];
    __shared__ float cnt[256];
    int tid = threadIdx.x; // blockDim = 256

    for (int i = tid; i < BINS; i += 256) conf[i] = confg[i];
    __syncthreads();

    if (tid < L) {
        float s = 0.f;
        for (int t = 0; t < L; ++t) s += conf[tid * L + t];
        area_p[tid] = s;
    }
    if (tid >= 128 && tid < 128 + L) {
        int t = tid - 128;
        float s = 0.f;
        for (int p = 0; p < L; ++p) s += conf[p * L + t];
        area_t[t] = s;
    }
    __syncthreads();

    float c = 0.f, k = 0.f;
    if (tid >= 1 && tid < L) {
        int p = tid;
        if (area_p[p] > 0.f) {
            float ap = area_p[p];
            float best = 0.f;
            for (int t = 1; t < L; ++t) {
                float inter = conf[p * L + t];
                float uni = ap + area_t[t] - inter;
                float iou = (uni > 0.f) ? inter / fmaxf(uni, 1.f) : 0.f;
                best = fmaxf(best, iou);
            }
            c = 1.f - best;
            k = 1.f;
        }
    }
    if (tid >= 129 && tid < 128 + L) {
        int t = tid - 128;
        if (area_t[t] > 0.f) {
            float at = area_t[t];
            float best = 0.f;
            for (int p = 1; p < L; ++p) {
                float inter = conf[p * L + t];
                float uni = area_p[p] + at - inter;
                float iou = (uni > 0.f) ? inter / fmaxf(uni, 1.f) : 0.f;
                best = fmaxf(best, iou);
            }
            c = 1.f - best;
            k = 1.f;
        }
    }
    contrib[tid] = c;
    cnt[tid] = k;
    __syncthreads();

    for (int s = 128; s > 0; s >>= 1) {
        if (tid < s) {
            contrib[tid] += contrib[tid + s];
            cnt[tid] += cnt[tid + s];
        }
        __syncthreads();
    }
    if (tid == 0) {
        float n_inst = cnt[0];
        out[0] = (n_inst > 0.f) ? (contrib[0] / fmaxf(n_inst, 1.f)) : 0.f;
    }
}

extern "C" void kernel_launch(void* const* d_in, const int* in_sizes, int n_in,
                              void* d_out, int out_size, void* d_ws, size_t ws_size,
                              hipStream_t stream) {
    const int* pred = (const int*)d_in[0];
    const int* truem = (const int*)d_in[1];
    float* out = (float*)d_out;
    int n = in_sizes[0];
    int n4 = n >> 2;

    // workspace layout: [NB * BINS u32 block hists][BINS float conf]
    size_t per_hist = (size_t)BINS * sizeof(unsigned int);
    int NB = 256;
    size_t need = (size_t)NB * per_hist + BINS * sizeof(float);
    while (NB > 1 && need > ws_size) {
        NB >>= 1;
        need = (size_t)NB * per_hist + BINS * sizeof(float);
    }
    unsigned int* block_hist = (unsigned int*)d_ws;
    float* conf = (float*)((char*)d_ws + (size_t)NB * per_hist);

    hist_kernel<<<NB, 256, 0, stream>>>(pred, truem, block_hist, n, n4);
    reduce_kernel<<<(BINS + 255) / 256, 256, 0, stream>>>(block_hist, conf, NB);
    finalize_kernel<<<1, 256, 0, stream>>>(conf, out);
}

// Round 4
// 95.912 us; speedup vs baseline: 1.2469x; 1.2469x over previous
//
#include <hip/hip_runtime.h>

#define L 65
#define BINS (L * L)
#define NCHUNK 8

// ---------------- Kernel 1: per-block LDS histogram ----------------
// 512 blocks x 1024 threads: 2 blocks/CU, 32 waves/CU (full occupancy).
// Each thread does only ~2 grid-stride iterations -> loads fully in flight.
__global__ __launch_bounds__(1024) void hist_kernel(const int* __restrict__ pred,
                                                    const int* __restrict__ truem,
                                                    unsigned int* __restrict__ block_hist,
                                                    int n, int n4) {
    __shared__ unsigned int sh[BINS];
    for (int i = threadIdx.x; i < BINS; i += blockDim.x) sh[i] = 0u;
    __syncthreads();

    const int4* p4 = (const int4*)pred;
    const int4* t4 = (const int4*)truem;
    int stride = gridDim.x * blockDim.x;
    int gtid = blockIdx.x * blockDim.x + threadIdx.x;

    for (int i = gtid; i < n4; i += stride) {
        int4 p = p4[i];
        int4 t = t4[i];
        atomicAdd(&sh[p.x * L + t.x], 1u);
        atomicAdd(&sh[p.y * L + t.y], 1u);
        atomicAdd(&sh[p.z * L + t.z], 1u);
        atomicAdd(&sh[p.w * L + t.w], 1u);
    }
    // scalar tail (n not divisible by 4)
    for (int i = n4 * 4 + gtid; i < n; i += stride) {
        atomicAdd(&sh[pred[i] * L + truem[i]], 1u);
    }
    __syncthreads();

    unsigned int* dst = block_hist + (size_t)blockIdx.x * BINS;
    for (int i = threadIdx.x; i < BINS; i += blockDim.x) dst[i] = sh[i];
}

// ---------------- Kernel 2: column-sum block hists -> partial[NCHUNK][BINS] ----
// 2D grid: x covers bins (coalesced across threads), y = chunk of rows.
// Each thread sums only nb/NCHUNK rows -> short independent-load loop.
__global__ void reduce_kernel(const unsigned int* __restrict__ block_hist,
                              float* __restrict__ partial,
                              int nb, int rows_per_chunk) {
    int bin = blockIdx.x * blockDim.x + threadIdx.x;
    if (bin >= BINS) return;
    int c = blockIdx.y;
    int r0 = c * rows_per_chunk;
    int r1 = r0 + rows_per_chunk;
    if (r1 > nb) r1 = nb;
    unsigned int s = 0u;
    for (int r = r0; r < r1; ++r) s += block_hist[(size_t)r * BINS + bin];
    partial[(size_t)c * BINS + bin] = (float)s;
}

// ---------------- Kernel 3: sum partials + tiny IoU epilogue ----------------
__global__ void finalize_kernel(const float* __restrict__ partial,
                                float* __restrict__ out) {
    __shared__ float conf[BINS];
    __shared__ float area_p[L];
    __shared__ float area_t[L];
    __shared__ float contrib[256];
    __shared__ float cnt[256];
    int tid = threadIdx.x; // blockDim = 256

    for (int i = tid; i < BINS; i += 256) {
        float s = 0.f;
        #pragma unroll
        for (int c = 0; c < NCHUNK; ++c) s += partial[(size_t)c * BINS + i];
        conf[i] = s;
    }
    __syncthreads();

    if (tid < L) {
        float s = 0.f;
        for (int t = 0; t < L; ++t) s += conf[tid * L + t];
        area_p[tid] = s;
    }
    if (tid >= 128 && tid < 128 + L) {
        int t = tid - 128;
        float s = 0.f;
        for (int p = 0; p < L; ++p) s += conf[p * L + t];
        area_t[t] = s;
    }
    __syncthreads();

    float c = 0.f, k = 0.f;
    if (tid >= 1 && tid < L) {
        int p = tid;
        if (area_p[p] > 0.f) {
            float ap = area_p[p];
            float best = 0.f;
            for (int t = 1; t < L; ++t) {
                float inter = conf[p * L + t];
                float uni = ap + area_t[t] - inter;
                float iou = (uni > 0.f) ? inter / fmaxf(uni, 1.f) : 0.f;
                best = fmaxf(best, iou);
            }
            c = 1.f - best;
            k = 1.f;
        }
    }
    if (tid >= 129 && tid < 128 + L) {
        int t = tid - 128;
        if (area_t[t] > 0.f) {
            float at = area_t[t];
            float best = 0.f;
            for (int p = 1; p < L; ++p) {
                float inter = conf[p * L + t];
                float uni = area_p[p] + at - inter;
                float iou = (uni > 0.f) ? inter / fmaxf(uni, 1.f) : 0.f;
                best = fmaxf(best, iou);
            }
            c = 1.f - best;
            k = 1.f;
        }
    }
    contrib[tid] = c;
    cnt[tid] = k;
    __syncthreads();

    for (int s = 128; s > 0; s >>= 1) {
        if (tid < s) {
            contrib[tid] += contrib[tid + s];
            cnt[tid] += cnt[tid + s];
        }
        __syncthreads();
    }
    if (tid == 0) {
        float n_inst = cnt[0];
        out[0] = (n_inst > 0.f) ? (contrib[0] / fmaxf(n_inst, 1.f)) : 0.f;
    }
}

extern "C" void kernel_launch(void* const* d_in, const int* in_sizes, int n_in,
                              void* d_out, int out_size, void* d_ws, size_t ws_size,
                              hipStream_t stream) {
    const int* pred = (const int*)d_in[0];
    const int* truem = (const int*)d_in[1];
    float* out = (float*)d_out;
    int n = in_sizes[0];
    int n4 = n >> 2;

    // workspace layout: [NB * BINS u32 block hists][NCHUNK * BINS float partial]
    size_t per_hist = (size_t)BINS * sizeof(unsigned int);
    int NB = 512;
    size_t need = (size_t)NB * per_hist + (size_t)NCHUNK * BINS * sizeof(float);
    while (NB > 1 && need > ws_size) {
        NB >>= 1;
        need = (size_t)NB * per_hist + (size_t)NCHUNK * BINS * sizeof(float);
    }
    unsigned int* block_hist = (unsigned int*)d_ws;
    float* partial = (float*)((char*)d_ws + (size_t)NB * per_hist);

    int rows_per_chunk = (NB + NCHUNK - 1) / NCHUNK;

    hist_kernel<<<NB, 1024, 0, stream>>>(pred, truem, block_hist, n, n4);

    dim3 rgrid((BINS + 255) / 256, NCHUNK);
    reduce_kernel<<<rgrid, 256, 0, stream>>>(block_hist, partial, NB, rows_per_chunk);

    finalize_kernel<<<1, 256, 0, stream>>>(partial, out);
}